// Round 6
// baseline (136.291 us; speedup 1.0000x reference)
//
#include <hip/hip_runtime.h>

#define NN 100000
#define NE 600000
#define D  128

typedef __bf16 bf16x8 __attribute__((ext_vector_type(8)));
typedef __bf16 bf16x4 __attribute__((ext_vector_type(4)));
typedef float  f32x4  __attribute__((ext_vector_type(4)));

#define GB_CNT  ((NE + 255) / 256)     // 2344 blocks: edge-sized
#define GB_WP   8                      // w-prep blocks
#define GB_GEMM ((NN / 16 + 3) / 4)    // 1563 blocks: gemm tiles

__device__ inline float bflo(unsigned int v) {
    unsigned int t = v << 16; float f; __builtin_memcpy(&f, &t, 4); return f;
}
__device__ inline float bfhi(unsigned int v) {
    unsigned int t = v & 0xffff0000u; float f; __builtin_memcpy(&f, &t, 4); return f;
}

// ------------------------------------------------ A: count_deg ∥ W-prep ∥ zero-row
__global__ __launch_bounds__(256) void k_A(const int* __restrict__ dst, int* __restrict__ cnt,
                                           const float* __restrict__ W, __bf16* __restrict__ wf,
                                           __bf16* __restrict__ g) {
    if (blockIdx.x < GB_CNT) {
        int e = blockIdx.x * 256 + threadIdx.x;
        if (e < NE) {
            int d = dst[e];
            if ((unsigned)d < (unsigned)NN) atomicAdd(&cnt[d], 1);
        }
    } else {
        int t = (blockIdx.x - GB_CNT) * 256 + threadIdx.x;   // 0..2047
        if (t < D) g[(size_t)NN * D + t] = (__bf16)0.f;      // zero row for masked gathers
        int lane = t & 63, ct = (t >> 6) & 7, kt = t >> 9;
        int col = ct * 16 + (lane & 15);
        int k0  = kt * 32 + ((lane >> 4) & 3) * 8;
        const float* wp = W + (size_t)col * D + k0;
        __bf16* o = wf + (size_t)t * 8;
        #pragma unroll
        for (int j = 0; j < 8; ++j) o[j] = (__bf16)wp[j];
    }
}

// ------------------------------------------------ scan -> meta{beg,end,dinv}, cur
__global__ __launch_bounds__(256) void k_off2(const int* __restrict__ cnt, int* __restrict__ gctr,
                                              int4* __restrict__ meta, int* __restrict__ cur) {
    __shared__ int s[256];
    __shared__ int base;
    int t = threadIdx.x, b = blockIdx.x;
    int i = b * 256 + t;
    int v = (i < NN) ? cnt[i] : 0;
    s[t] = v;
    __syncthreads();
    for (int d = 1; d < 256; d <<= 1) {
        int u = (t >= d) ? s[t - d] : 0;
        __syncthreads();
        s[t] += u;
        __syncthreads();
    }
    if (t == 255) base = atomicAdd(gctr, s[255]);
    __syncthreads();
    if (i < NN) {
        int ex = base + s[t] - v;
        cur[i] = ex;
        meta[i] = make_int4(ex, ex + v, __float_as_int(rsqrtf((float)(v + 1))), 0);
    }
}

// ------------------------------------------------ C: CSR fill FIRST, then gemm (W·x^T)
// Fill blocks lead so their long-latency atomics issue early; gemm blocks
// stream memory/MFMA work underneath them.
__global__ __launch_bounds__(256) void k_C(const float* __restrict__ x,
                                           const __bf16* __restrict__ wf,
                                           const int4* __restrict__ meta,
                                           __bf16* __restrict__ g,
                                           const int* __restrict__ src,
                                           const int* __restrict__ dst,
                                           int* __restrict__ cur, int* __restrict__ adj) {
    if (blockIdx.x < GB_CNT) {
        int e = blockIdx.x * 256 + threadIdx.x;
        if (e >= NE) return;
        int d = dst[e], s = src[e];
        if ((unsigned)d >= (unsigned)NN || (unsigned)s >= (unsigned)NN) return;
        adj[atomicAdd(&cur[d], 1)] = s;
    } else {
        int gid = (blockIdx.x - GB_CNT) * 4 + (threadIdx.x >> 6);
        if (gid >= NN / 16) return;
        int lane = threadIdx.x & 63;
        int node = gid * 16 + (lane & 15);
        int kg   = lane >> 4;

        f32x4 acc[8];
        #pragma unroll
        for (int ct = 0; ct < 8; ++ct) acc[ct] = (f32x4){0.f, 0.f, 0.f, 0.f};

        #pragma unroll
        for (int kt = 0; kt < 4; ++kt) {
            const float4* xp = (const float4*)(x + (size_t)node * D + kt * 32 + kg * 8);
            float4 x0 = xp[0];
            float4 x1 = xp[1];
            bf16x8 a;
            a[0] = (__bf16)x0.x; a[1] = (__bf16)x0.y; a[2] = (__bf16)x0.z; a[3] = (__bf16)x0.w;
            a[4] = (__bf16)x1.x; a[5] = (__bf16)x1.y; a[6] = (__bf16)x1.z; a[7] = (__bf16)x1.w;
            const bf16x8* wfp = (const bf16x8*)wf + (size_t)kt * 512 + lane;
            #pragma unroll
            for (int ct = 0; ct < 8; ++ct) {
                bf16x8 b = wfp[ct * 64];
                acc[ct] = __builtin_amdgcn_mfma_f32_16x16x32_bf16(b, a, acc[ct], 0, 0, 0);
            }
        }

        float dv = __int_as_float(((const int*)meta)[4 * node + 2]);
        #pragma unroll
        for (int ct = 0; ct < 8; ++ct) {
            bf16x4 o;
            #pragma unroll
            for (int i = 0; i < 4; ++i) o[i] = (__bf16)(acc[ct][i] * dv);
            *(bf16x4*)(g + (size_t)node * D + ct * 16 + kg * 4) = o;
        }
    }
}

// ------------------------------------------------ gather-aggregate, 4 nodes/wave (quarter-wave)
// 16 lanes per node, uint4 (16B = 8 bf16) per lane -> one gather instruction
// fetches 4 full 256B rows (one per quarter). Exhausted quarters are
// exec-masked off, so no wasted gather traffic.
__global__ __launch_bounds__(256) void k_agg(const float* __restrict__ x,
                                             const __bf16* __restrict__ g,
                                             const int4* __restrict__ meta,
                                             const float* __restrict__ bias,
                                             const int* __restrict__ adj,
                                             float* __restrict__ out) {
    int wave = blockIdx.x * 4 + (threadIdx.x >> 6);
    int lane = threadIdx.x & 63;
    int q    = lane >> 4;            // 0..3
    int l4   = lane & 15;
    int node = wave * 4 + q;         // wave < 25000 -> node < NN
    int c0   = l4 * 8;               // bf16 feature base: 16 lanes x 8 = 128

    int4 m = meta[node];
    int beg = m.x, end = m.y;
    float dv = __int_as_float(m.z);

    const float4* xp = (const float4*)(x + (size_t)node * D + c0);
    float4 xv0 = xp[0], xv1 = xp[1];
    const float4* bp = (const float4*)(bias + c0);
    float4 bv0 = bp[0], bv1 = bp[1];

    uint4 u = *(const uint4*)(g + (size_t)node * D + c0);   // self loop
    float a0 = bflo(u.x), a1 = bfhi(u.x), a2 = bflo(u.y), a3 = bfhi(u.y);
    float a4 = bflo(u.z), a5 = bfhi(u.z), a6 = bflo(u.w), a7 = bfhi(u.w);

    for (int i = beg; i < end; i += 4) {
        int s0 = adj[i];
        int s1 = (i + 1 < end) ? adj[i + 1] : NN;
        int s2 = (i + 2 < end) ? adj[i + 2] : NN;
        int s3 = (i + 3 < end) ? adj[i + 3] : NN;
        uint4 v0 = *(const uint4*)(g + (size_t)s0 * D + c0);
        uint4 v1 = *(const uint4*)(g + (size_t)s1 * D + c0);
        uint4 v2 = *(const uint4*)(g + (size_t)s2 * D + c0);
        uint4 v3 = *(const uint4*)(g + (size_t)s3 * D + c0);
        a0 += bflo(v0.x); a1 += bfhi(v0.x); a2 += bflo(v0.y); a3 += bfhi(v0.y);
        a4 += bflo(v0.z); a5 += bfhi(v0.z); a6 += bflo(v0.w); a7 += bfhi(v0.w);
        a0 += bflo(v1.x); a1 += bfhi(v1.x); a2 += bflo(v1.y); a3 += bfhi(v1.y);
        a4 += bflo(v1.z); a5 += bfhi(v1.z); a6 += bflo(v1.w); a7 += bfhi(v1.w);
        a0 += bflo(v2.x); a1 += bfhi(v2.x); a2 += bflo(v2.y); a3 += bfhi(v2.y);
        a4 += bflo(v2.z); a5 += bfhi(v2.z); a6 += bflo(v2.w); a7 += bfhi(v2.w);
        a0 += bflo(v3.x); a1 += bfhi(v3.x); a2 += bflo(v3.y); a3 += bfhi(v3.y);
        a4 += bflo(v3.z); a5 += bfhi(v3.z); a6 += bflo(v3.w); a7 += bfhi(v3.w);
    }

    f32x4 r0, r1;
    r0[0] = xv0.x + fmaxf(fmaf(dv, a0, bv0.x), 0.f);
    r0[1] = xv0.y + fmaxf(fmaf(dv, a1, bv0.y), 0.f);
    r0[2] = xv0.z + fmaxf(fmaf(dv, a2, bv0.z), 0.f);
    r0[3] = xv0.w + fmaxf(fmaf(dv, a3, bv0.w), 0.f);
    r1[0] = xv1.x + fmaxf(fmaf(dv, a4, bv1.x), 0.f);
    r1[1] = xv1.y + fmaxf(fmaf(dv, a5, bv1.y), 0.f);
    r1[2] = xv1.z + fmaxf(fmaf(dv, a6, bv1.z), 0.f);
    r1[3] = xv1.w + fmaxf(fmaf(dv, a7, bv1.w), 0.f);
    f32x4* op = (f32x4*)(out + (size_t)node * D + c0);
    __builtin_nontemporal_store(r0, op);
    __builtin_nontemporal_store(r1, op + 1);
}

// ------------------------------------------------ launch
extern "C" void kernel_launch(void* const* d_in, const int* in_sizes, int n_in,
                              void* d_out, int out_size, void* d_ws, size_t ws_size,
                              hipStream_t stream) {
    const float* x    = (const float*)d_in[0];
    const int*   ei   = (const int*)d_in[1];      // [2][NE], int32
    const float* W    = (const float*)d_in[2];    // [D][D]
    const float* bias = (const float*)d_in[3];    // [D]
    float* out = (float*)d_out;

    const int* src = ei;
    const int* dst = ei + NE;

    char* p = (char*)d_ws;
    auto take = [&](size_t bytes) {
        char* q = p;
        p += (bytes + 255) & ~(size_t)255;
        return q;
    };
    int*    cnt  = (int*)take((size_t)NN * 4);
    int*    gctr = (int*)take(256);                       // adjacent to cnt -> one memset
    int4*   meta = (int4*)take((size_t)NN * 16);
    int*    cur  = (int*)take((size_t)NN * 4);
    int*    adj  = (int*)take((size_t)(NE + 16) * 4);
    __bf16* wf   = (__bf16*)take((size_t)2048 * 8 * 2);
    __bf16* g    = (__bf16*)take((size_t)(NN + 1) * D * 2);   // +1 zero row

    size_t cntPad = (((size_t)NN * 4 + 255) & ~(size_t)255);
    (void)hipMemsetAsync(cnt, 0, cntPad + 256, stream);   // zeroes cnt + gctr

    k_A   <<<GB_CNT + GB_WP, 256, 0, stream>>>(dst, cnt, W, wf, g);
    k_off2<<<(NN + 255) / 256, 256, 0, stream>>>(cnt, gctr, meta, cur);
    k_C   <<<GB_CNT + GB_GEMM, 256, 0, stream>>>(x, wf, meta, g, src, dst, cur, adj);
    k_agg <<<NN / 16, 256, 0, stream>>>(x, g, meta, bias, adj, out);
}